// Round 4
// baseline (30.852 us; speedup 1.0000x reference)
//
#include <hip/hip_runtime.h>
#include <math.h>

// Chamfer distance, B=8, N=M=4096, D=3, fp32.
// dist1[n] = max(sq1[n] + min_m(sq2[m] - 2 a.b[m]), 0); mean(sqrt), both dirs.
//
// R4: occupancy fix. R1/R3 both ran 2 waves/SIMD (66KB LDS -> 2 blocks/CU)
// and were latency-bound at ~45% VALU. Now: 2048-pt b-chunks (32KB LDS),
// PA=16, <=128 VGPR -> 4 blocks/CU, 4 waves/SIMD. Lane l owns b-points
// t*64+l (stride-1 conflict-free ds_read_b128). Cross-lane min via one
// LDS transpose + single-wave pass (no 96-bpermute tail).
// VALU floor: 268M pairs * 3.5 ops / 32768 lanes/cyc ~ 28.7K cyc ~ 12 us.

#define NPTS 4096
#define BATCH 8
#define CHUNK 2048
#define NCHUNK (NPTS / CHUNK)        // 2
#define PA 16
#define WAVES 4                      // 256 threads
#define APB (WAVES * PA)             // 64 a-points per block
#define ABLK (NPTS / APB)            // 64
#define NBLOCKS (2 * BATCH * ABLK)   // 1024 -> exactly 4 blocks/CU
#define RSTRIDE 68                   // floats; 64 rows, 16B-aligned rows

__global__ __launch_bounds__(256, 4) void chamfer_main(
    const float* __restrict__ pcs1, const float* __restrict__ pcs2,
    float* __restrict__ partials)
{
    __shared__ float4 bpts[CHUNK];   // 32 KB; reused as reduce scratch

    const int bid = blockIdx.x;
    const int dir = bid >> 9;        // 512 blocks per direction
    const int b   = (bid >> 6) & 7;
    const int ach = bid & 63;

    const float* A  = dir ? pcs2 : pcs1;
    const float* Bp = dir ? pcs1 : pcs2;
    const float* abase = A  + (size_t)b * NPTS * 3;
    const float* bbase = Bp + (size_t)b * NPTS * 3;

    const int tid = threadIdx.x;
    const int w   = tid >> 6;
    const int l   = tid & 63;

    // ---- per-wave a-points (wave-uniform -> scalarized loads) ----
    const int apt = ach * APB + w * PA;
    float nax[PA], nay[PA], naz[PA], tmin[PA];
#pragma unroll
    for (int p = 0; p < PA; ++p) {
        float x = abase[(apt + p) * 3 + 0];
        float y = abase[(apt + p) * 3 + 1];
        float z = abase[(apt + p) * 3 + 2];
        nax[p]  = -2.0f * x;
        nay[p]  = -2.0f * y;
        naz[p]  = -2.0f * z;
        tmin[p] = 3.4e38f;
    }

    // ---- chunked sweep over the b-cloud ----
    for (int c = 0; c < NCHUNK; ++c) {
        if (c) __syncthreads();                 // prev compute done
#pragma unroll
        for (int i = 0; i < CHUNK / 256; ++i) { // stage 2048 pts
            int m  = i * 256 + tid;
            int gm = c * CHUNK + m;
            float x = bbase[gm * 3 + 0];
            float y = bbase[gm * 3 + 1];
            float z = bbase[gm * 3 + 2];
            bpts[m] = make_float4(x, y, z, fmaf(x, x, fmaf(y, y, z * z)));
        }
        __syncthreads();

        // 32 t-steps; lane l reads point t*64+l (stride-1, conflict-free)
#pragma unroll 2
        for (int t = 0; t < CHUNK / 64; t += 2) {
            float4 q0 = bpts[t * 64 + l];
            float4 q1 = bpts[t * 64 + 64 + l];
#pragma unroll
            for (int p = 0; p < PA; ++p) {
                float t0 = fmaf(nax[p], q0.x,
                           fmaf(nay[p], q0.y, fmaf(naz[p], q0.z, q0.w)));
                float t1 = fmaf(nax[p], q1.x,
                           fmaf(nay[p], q1.y, fmaf(naz[p], q1.z, q1.w)));
                tmin[p] = fminf(fminf(tmin[p], t0), t1);   // -> v_min3_f32
            }
        }
    }

    // ---- cross-lane min: transpose into LDS, single-wave min pass ----
    __syncthreads();                             // done with bpts as float4
    float* lds2 = (float*)bpts;                  // 64 x 68 floats = 17 KB
#pragma unroll
    for (int p = 0; p < PA; ++p)
        lds2[(w * PA + p) * RSTRIDE + l] = tmin[p];
    __syncthreads();

    if (tid < 64) {
        const int g = tid;                       // block-local a-point
        float m = 3.4e38f;
        const float4* row = (const float4*)&lds2[g * RSTRIDE];
#pragma unroll
        for (int i = 0; i < 16; ++i) {
            float4 v = row[i];
            m = fminf(fminf(m, fminf(v.x, v.y)), fminf(v.z, v.w));
        }
        const int ap = ach * APB + g;
        float x = abase[ap * 3 + 0];
        float y = abase[ap * 3 + 1];
        float z = abase[ap * 3 + 2];
        float sq = fmaf(x, x, fmaf(y, y, z * z));
        float s = sqrtf(fmaxf(sq + m, 0.0f));    // clamp cancellation
#pragma unroll
        for (int off = 1; off < 64; off <<= 1)
            s += __shfl_xor(s, off, 64);
        if (g == 0) partials[bid] = s;
    }
}

__global__ __launch_bounds__(256) void chamfer_final(
    const float* __restrict__ partials, int n, float* __restrict__ out)
{
    __shared__ float ws[4];
    const int t = threadIdx.x;
    float v = 0.0f;
    for (int i = t; i < n; i += 256) v += partials[i];
#pragma unroll
    for (int off = 1; off < 64; off <<= 1) v += __shfl_xor(v, off, 64);
    if ((t & 63) == 0) ws[t >> 6] = v;
    __syncthreads();
    if (t == 0)
        out[0] = (ws[0] + ws[1] + ws[2] + ws[3]) * (1.0f / 65536.0f);
    // loss = 0.5*(sum1/32768 + sum2/32768) = (sum1+sum2)/65536
}

extern "C" void kernel_launch(void* const* d_in, const int* in_sizes, int n_in,
                              void* d_out, int out_size, void* d_ws, size_t ws_size,
                              hipStream_t stream) {
    const float* pcs1 = (const float*)d_in[0];
    const float* pcs2 = (const float*)d_in[1];
    float* out      = (float*)d_out;
    float* partials = (float*)d_ws;   // NBLOCKS floats = 4 KB scratch

    chamfer_main <<<dim3(NBLOCKS), dim3(256), 0, stream>>>(pcs1, pcs2, partials);
    chamfer_final<<<dim3(1),       dim3(256), 0, stream>>>(partials, NBLOCKS, out);
}

// Round 5
// 30.466 us; speedup vs baseline: 1.0127x; 1.0127x over previous
//
#include <hip/hip_runtime.h>
#include <math.h>

// Chamfer distance, B=8, N=M=4096, D=3, fp32.
// dist1[n] = max(sq1[n] + min_m(sq2[m] - 2 a.b[m]), 0); mean(sqrt), both dirs.
//
// R5: packed-fp32 inner loop. v_pk_fma_f32 (VOP3P, 2 FMA/inst) over b-point
// PAIRS stored pair-SoA in LDS: bx[j]=(x0,x1,y0,y1), bz[j]=(z0,z1,w0,w1),
// so one ds_read_b128 yields two packed operands. a-coeffs packed 2-per-pair,
// broadcast via op_sel (lo for even a-point, hi for odd) -> 48 coeff VGPRs.
// Per 2 b-points per a-point: 3 pk_fma + 1 min3 = 4 inst (was 7).
// VALU floor: 4 waves/SIMD x 2048 inst x 2 cyc = 16.4K cyc ~ 6.8 us.

typedef float f32x2 __attribute__((ext_vector_type(2)));

#define NPTS 4096
#define BATCH 8
#define CPAIRS 1024                  // b-point pairs per LDS chunk (2048 pts)
#define NCHUNK 2
#define PA 16                        // a-points per thread
#define APB 64                       // a-points per block (4 waves * 16)
#define NBLOCKS 1024                 // 2 dir * 8 batch * 64 chunks = 4/CU
#define RSTRIDE 68                   // tail-transpose row stride (floats)

// d = c.lo * q + acc  (c.lo broadcast to both halves)
__device__ __forceinline__ f32x2 pk_fma_lo(f32x2 c, f32x2 q, f32x2 acc) {
    f32x2 d;
    asm("v_pk_fma_f32 %0, %1, %2, %3 op_sel:[0,0,0] op_sel_hi:[0,1,1]"
        : "=v"(d) : "v"(c), "v"(q), "v"(acc));
    return d;
}
// d = c.hi * q + acc  (c.hi broadcast to both halves)
__device__ __forceinline__ f32x2 pk_fma_hi(f32x2 c, f32x2 q, f32x2 acc) {
    f32x2 d;
    asm("v_pk_fma_f32 %0, %1, %2, %3 op_sel:[1,0,0] op_sel_hi:[1,1,1]"
        : "=v"(d) : "v"(c), "v"(q), "v"(acc));
    return d;
}
__device__ __forceinline__ void vmin3(float& acc, float a, float b) {
    asm("v_min3_f32 %0, %1, %2, %3" : "=v"(acc) : "v"(acc), "v"(a), "v"(b));
}

__global__ __launch_bounds__(256, 4) void chamfer_main(
    const float* __restrict__ pcs1, const float* __restrict__ pcs2,
    float* __restrict__ partials)
{
    __shared__ float4 lds[2 * CPAIRS];        // 32 KB; reused by tail reduce
    float4* bx = lds;                         // (x0,x1,y0,y1) per pair
    float4* bz = lds + CPAIRS;                // (z0,z1,w0,w1) per pair

    const int bid = blockIdx.x;
    const int dir = bid >> 9;                 // 512 blocks per direction
    const int b   = (bid >> 6) & 7;
    const int ach = bid & 63;

    const float* A  = dir ? pcs2 : pcs1;
    const float* Bp = dir ? pcs1 : pcs2;
    const float* abase = A  + (size_t)b * NPTS * 3;
    const float* bbase = Bp + (size_t)b * NPTS * 3;

    const int tid = threadIdx.x;
    const int w   = tid >> 6;
    const int l   = tid & 63;

    // ---- a-point coefficients: 2 a-points packed per f32x2 ----
    const int apt = ach * APB + w * PA;
    f32x2 cx[PA / 2], cy[PA / 2], cz[PA / 2];
    float tmin[PA];
#pragma unroll
    for (int p2 = 0; p2 < PA / 2; ++p2) {
        const float* s = abase + (size_t)(apt + 2 * p2) * 3;
        cx[p2] = (f32x2){-2.0f * s[0], -2.0f * s[3]};
        cy[p2] = (f32x2){-2.0f * s[1], -2.0f * s[4]};
        cz[p2] = (f32x2){-2.0f * s[2], -2.0f * s[5]};
        tmin[2 * p2]     = 3.4e38f;
        tmin[2 * p2 + 1] = 3.4e38f;
    }

    // ---- chunked sweep over the b-cloud ----
    for (int c = 0; c < NCHUNK; ++c) {
        if (c) __syncthreads();               // prev compute done
#pragma unroll
        for (int i = 0; i < CPAIRS / 256; ++i) {   // stage 1024 pairs
            int j  = i * 256 + tid;
            int gp = c * CPAIRS + j;
            const float* s = bbase + (size_t)gp * 6;
            float x0 = s[0], y0 = s[1], z0 = s[2];
            float x1 = s[3], y1 = s[4], z1 = s[5];
            bx[j] = make_float4(x0, x1, y0, y1);
            bz[j] = make_float4(z0, z1,
                                fmaf(x0, x0, fmaf(y0, y0, z0 * z0)),
                                fmaf(x1, x1, fmaf(y1, y1, z1 * z1)));
        }
        __syncthreads();

        // 16 t-steps; lane l reads pair t*64+l (stride-1, conflict-free)
#pragma unroll 4
        for (int t = 0; t < CPAIRS / 64; ++t) {
            float4 X = bx[t * 64 + l];
            float4 Z = bz[t * 64 + l];
            f32x2 qx = (f32x2){X.x, X.y};
            f32x2 qy = (f32x2){X.z, X.w};
            f32x2 qz = (f32x2){Z.x, Z.y};
            f32x2 qw = (f32x2){Z.z, Z.w};
#pragma unroll
            for (int p2 = 0; p2 < PA / 2; ++p2) {
                f32x2 d0 = pk_fma_lo(cz[p2], qz, qw);
                d0 = pk_fma_lo(cy[p2], qy, d0);
                d0 = pk_fma_lo(cx[p2], qx, d0);
                vmin3(tmin[2 * p2], d0.x, d0.y);
                f32x2 d1 = pk_fma_hi(cz[p2], qz, qw);
                d1 = pk_fma_hi(cy[p2], qy, d1);
                d1 = pk_fma_hi(cx[p2], qx, d1);
                vmin3(tmin[2 * p2 + 1], d1.x, d1.y);
            }
        }
    }

    // ---- cross-lane min: transpose into LDS, single-wave pass ----
    __syncthreads();                          // done with bx/bz
    float* lds2 = (float*)lds;                // 64 x 68 floats = 17.4 KB
#pragma unroll
    for (int p = 0; p < PA; ++p)
        lds2[(w * PA + p) * RSTRIDE + l] = tmin[p];
    __syncthreads();

    if (tid < 64) {
        const int g = tid;                    // block-local a-point
        float m = 3.4e38f;
        const float4* row = (const float4*)&lds2[g * RSTRIDE];
#pragma unroll
        for (int i = 0; i < 16; ++i) {
            float4 v = row[i];
            m = fminf(fminf(m, fminf(v.x, v.y)), fminf(v.z, v.w));
        }
        const int ap = ach * APB + g;
        float x = abase[ap * 3 + 0];
        float y = abase[ap * 3 + 1];
        float z = abase[ap * 3 + 2];
        float sq = fmaf(x, x, fmaf(y, y, z * z));
        float s = sqrtf(fmaxf(sq + m, 0.0f));  // clamp cancellation
#pragma unroll
        for (int off = 1; off < 64; off <<= 1)
            s += __shfl_xor(s, off, 64);
        if (g == 0) partials[bid] = s;
    }
}

__global__ __launch_bounds__(256) void chamfer_final(
    const float* __restrict__ partials, int n, float* __restrict__ out)
{
    __shared__ float ws[4];
    const int t = threadIdx.x;
    float v = 0.0f;
    for (int i = t; i < n; i += 256) v += partials[i];
#pragma unroll
    for (int off = 1; off < 64; off <<= 1) v += __shfl_xor(v, off, 64);
    if ((t & 63) == 0) ws[t >> 6] = v;
    __syncthreads();
    if (t == 0)
        out[0] = (ws[0] + ws[1] + ws[2] + ws[3]) * (1.0f / 65536.0f);
    // loss = 0.5*(sum1/32768 + sum2/32768) = (sum1+sum2)/65536
}

extern "C" void kernel_launch(void* const* d_in, const int* in_sizes, int n_in,
                              void* d_out, int out_size, void* d_ws, size_t ws_size,
                              hipStream_t stream) {
    const float* pcs1 = (const float*)d_in[0];
    const float* pcs2 = (const float*)d_in[1];
    float* out      = (float*)d_out;
    float* partials = (float*)d_ws;   // NBLOCKS floats = 4 KB scratch

    chamfer_main <<<dim3(NBLOCKS), dim3(256), 0, stream>>>(pcs1, pcs2, partials);
    chamfer_final<<<dim3(1),       dim3(256), 0, stream>>>(partials, NBLOCKS, out);
}